// Round 7
// baseline (133.801 us; speedup 1.0000x reference)
//
#include <hip/hip_runtime.h>

typedef unsigned short u16;
typedef float f32x4 __attribute__((ext_vector_type(4)));
typedef unsigned int u32x4 __attribute__((ext_vector_type(4)));
typedef unsigned short u16x4 __attribute__((ext_vector_type(4)));
typedef unsigned short u16x8 __attribute__((ext_vector_type(8)));
typedef __bf16 bf16x8 __attribute__((ext_vector_type(8)));

#define DEVFN static __device__ __forceinline__

DEVFN float bf2f(u16 u) {
    unsigned int i = ((unsigned int)u) << 16;
    float f;
    __builtin_memcpy(&f, &i, 4);
    return f;
}
DEVFN u16 f2bf(float f) {
    unsigned int i;
    __builtin_memcpy(&i, &f, 4);
    unsigned int r = i + 0x7fffu + ((i >> 16) & 1u);
    return (u16)(r >> 16);
}

DEVFN bf16x8 ldb(const u16* p) { return __builtin_bit_cast(bf16x8, *(const u16x8*)p); }

// 16x16x32: C/D: col=lane&15 (Brow), row=(lane>>4)*4+reg (Arow)  (HW-verified r2)
DEVFN f32x4 mfma16(bf16x8 a, bf16x8 b, f32x4 c) {
    return __builtin_amdgcn_mfma_f32_16x16x32_bf16(a, b, c, 0, 0, 0);
}

// ---------------- weight convert: fp32 -> bf16 ----------------
__global__ __launch_bounds__(256) void k_cvtw(const float* __restrict__ pt,
                                              const float* __restrict__ q,
                                              const float* __restrict__ k,
                                              const float* __restrict__ v,
                                              const float* __restrict__ o,
                                              const float* __restrict__ f,
                                              u16* __restrict__ dst) {
    int i = blockIdx.x * 256 + threadIdx.x;  // grid covers exactly 147456
    const float* s;
    int off;
    if (i < 65536)       { s = pt; off = i; }
    else if (i < 81920)  { s = q;  off = i - 65536; }
    else if (i < 98304)  { s = k;  off = i - 81920; }
    else if (i < 114688) { s = v;  off = i - 98304; }
    else if (i < 131072) { s = o;  off = i - 114688; }
    else                 { s = f;  off = i - 131072; }
    dst[i] = f2bf(s[off]);
}

// ---------------- per-batch mask sum + Q scale ----------------
__global__ __launch_bounds__(256) void k_nsum(const int* __restrict__ mask,
                                              int* __restrict__ nsumI,
                                              float* __restrict__ scaleQ) {
    __shared__ int sred[4];
    int tid = threadIdx.x, b = blockIdx.x;
    int4 mm = *(const int4*)&mask[(b << 10) + tid * 4];
    int part = mm.x + mm.y + mm.z + mm.w;
#pragma unroll
    for (int off = 1; off < 64; off <<= 1) part += __shfl_xor(part, off);
    if ((tid & 63) == 0) sred[tid >> 6] = part;
    __syncthreads();
    if (tid == 0) {
        int n = sred[0] + sred[1] + sred[2] + sred[3];
        nsumI[b] = n;
        // 0.5: QK uses K-doubled fragments (S = 2*dot); log2(e): exp2 softmax
        scaleQ[b] = 0.5f * rsqrtf((float)n) * 1.44269504089f;
    }
}

// ---------------- fused conv layer: LN + depthwise conv + pointwise GEMM + residual ----------------
__global__ __launch_bounds__(256) void k_convlayer(const float* __restrict__ x,
                                                   const u16* __restrict__ Wp,
                                                   const float* __restrict__ dw,
                                                   const float* __restrict__ db,
                                                   const float* __restrict__ pb,
                                                   float* __restrict__ dst) {
    __shared__ alignas(16) u16 lnv[38 * 128];    // LN'ed rows l0-3..l0+34
    __shared__ alignas(16) u16 convt[32 * 128];  // conv output, swizzled A-tile
    __shared__ alignas(16) u16 sW[128 * 128];    // pointwise W, swizzled
    __shared__ alignas(16) float sRes[32 * 128]; // fp32 residual rows
    int tid = threadIdx.x;
    int w = tid >> 6, l64 = tid & 63;
    int b = blockIdx.x >> 5, lt = blockIdx.x & 31;
    int l0 = lt << 5;
    const float* xb = x + ((size_t)(b << 10)) * 128;

#pragma unroll
    for (int j = 0; j < 8; j++) {
        int e = j * 256 + tid;
        int r = e >> 4, cc = e & 15;
        *(u32x4*)&sW[r * 128 + ((cc ^ (r & 15)) << 3)] = *(const u32x4*)&Wp[(r << 7) + (cc << 3)];
    }

    for (int r = w; r < 38; r += 4) {
        int gl = l0 - 3 + r;
        float2 v = {0.f, 0.f};
        bool ok = (gl >= 0) && (gl < 1024);
        if (ok) v = *(const float2*)&xb[(size_t)gl * 128 + (l64 << 1)];
        if (r >= 3 && r < 35) *(float2*)&sRes[(r - 3) * 128 + (l64 << 1)] = v;
        float s = v.x + v.y, q = v.x * v.x + v.y * v.y;
#pragma unroll
        for (int off = 1; off < 64; off <<= 1) {
            s += __shfl_xor(s, off);
            q += __shfl_xor(q, off);
        }
        float mean = s * (1.0f / 128.0f);
        float var = q * (1.0f / 128.0f) - mean * mean;
        float rs = rsqrtf(var + 1e-5f);
        unsigned int pk = 0;
        if (ok)
            pk = (unsigned int)f2bf((v.x - mean) * rs) | ((unsigned int)f2bf((v.y - mean) * rs) << 16);
        *(unsigned int*)&lnv[r * 128 + (l64 << 1)] = pk;
    }
    __syncthreads();

    // depthwise conv, sliding window: 14 LDS reads per thread, values kept in regs
    int cp = tid & 63;
    int ls = tid >> 6;
    float w0[7], w1[7];
#pragma unroll
    for (int k = 0; k < 7; k++) {
        w0[k] = dw[(cp * 2) * 7 + k];
        w1[k] = dw[(cp * 2 + 1) * 7 + k];
    }
    float b0 = db[cp * 2], b1 = db[cp * 2 + 1];
    float v0[14], v1[14];
#pragma unroll
    for (int k = 0; k < 14; k++) {
        unsigned int pk = *(const unsigned int*)&lnv[(ls * 8 + k) * 128 + (cp << 1)];
        v0[k] = bf2f((u16)(pk & 0xffffu));
        v1[k] = bf2f((u16)(pk >> 16));
    }
#pragma unroll
    for (int rr = 0; rr < 8; rr++) {
        int l = ls * 8 + rr;
        float a0 = b0, a1 = b1;
#pragma unroll
        for (int k = 0; k < 7; k++) {
            a0 += v0[rr + k] * w0[k];
            a1 += v1[rr + k] * w1[k];
        }
        int cc = cp >> 2;
        *(unsigned int*)&convt[l * 128 + ((cc ^ (l & 15)) << 3) + ((cp & 3) << 1)] =
            (unsigned int)f2bf(a0) | ((unsigned int)f2bf(a1) << 16);
    }
    __syncthreads();

    int row16 = l64 & 15, g = l64 >> 4;
    int mh = w >> 1, nh = w & 1;
    f32x4 zf = {0.f, 0.f, 0.f, 0.f};
    f32x4 acc[4] = {zf, zf, zf, zf};
#pragma unroll
    for (int kk = 0; kk < 4; kk++) {
        int chunk = ((kk * 4 + g) ^ row16) << 3;
        bf16x8 a = ldb(&convt[(mh * 16 + row16) * 128 + chunk]);
#pragma unroll
        for (int n = 0; n < 4; n++) {
            bf16x8 bfr = ldb(&sW[(nh * 64 + n * 16 + row16) * 128 + chunk]);
            acc[n] = mfma16(a, bfr, acc[n]);
        }
    }
#pragma unroll
    for (int n = 0; n < 4; n++) {
        int col = nh * 64 + n * 16 + row16;
        float bi = pb[col];
#pragma unroll
        for (int r = 0; r < 4; r++) {
            int lr = mh * 16 + g * 4 + r;
            float val = acc[n][r] + bi + sRes[lr * 128 + col];
            dst[((size_t)(b << 10) + l0 + lr) * 128 + col] = val;
        }
    }
}

// ---------------- fused LN + GEMM: Y = LN(X) @ W^T -> bf16 (QKV; Q pre-scaled) ----------------
__global__ __launch_bounds__(256) void k_lngemm(const float* __restrict__ x,
                                                const u16* __restrict__ Wb, int wstride,
                                                u16* __restrict__ dstb, int dstride,
                                                const float* __restrict__ scaleQ) {
    __shared__ alignas(16) u16 sX[64 * 128];
    __shared__ alignas(16) u16 sW[128 * 128];
    const u16* Wp = Wb + (size_t)blockIdx.y * wstride;
    dstb += (size_t)blockIdx.y * dstride;
    float qs = (blockIdx.y == 0) ? scaleQ[blockIdx.x >> 4] : 1.0f;
    int tid = threadIdx.x;
    int w = tid >> 6, l64 = tid & 63;
    int rbase = blockIdx.x * 64;

#pragma unroll
    for (int j = 0; j < 8; j++) {
        int e = j * 256 + tid;
        int r = e >> 4, cc = e & 15;
        *(u32x4*)&sW[r * 128 + ((cc ^ (r & 15)) << 3)] = *(const u32x4*)&Wp[(r << 7) + (cc << 3)];
    }
    for (int r = w; r < 64; r += 4) {
        float2 v = *(const float2*)&x[((size_t)(rbase + r)) * 128 + (l64 << 1)];
        float s = v.x + v.y, q = v.x * v.x + v.y * v.y;
#pragma unroll
        for (int off = 1; off < 64; off <<= 1) {
            s += __shfl_xor(s, off);
            q += __shfl_xor(q, off);
        }
        float mean = s * (1.0f / 128.0f);
        float var = q * (1.0f / 128.0f) - mean * mean;
        float rs = rsqrtf(var + 1e-5f);
        unsigned int pk = (unsigned int)f2bf((v.x - mean) * rs) |
                          ((unsigned int)f2bf((v.y - mean) * rs) << 16);
        int cc = l64 >> 2;
        *(unsigned int*)&sX[r * 128 + ((cc ^ (r & 15)) << 3) + ((l64 & 3) << 1)] = pk;
    }
    __syncthreads();

    int row16 = l64 & 15, g = l64 >> 4;
    f32x4 zf = {0.f, 0.f, 0.f, 0.f};
    f32x4 acc[8];
#pragma unroll
    for (int n = 0; n < 8; n++) acc[n] = zf;
#pragma unroll
    for (int kk = 0; kk < 4; kk++) {
        int chunk = ((kk * 4 + g) ^ row16) << 3;
        bf16x8 a = ldb(&sX[(w * 16 + row16) * 128 + chunk]);
#pragma unroll
        for (int n = 0; n < 8; n++) {
            bf16x8 bfr = ldb(&sW[(n * 16 + row16) * 128 + chunk]);
            acc[n] = mfma16(a, bfr, acc[n]);
        }
    }
    int r0 = rbase + w * 16 + g * 4;
#pragma unroll
    for (int n = 0; n < 8; n++) {
        int col = n * 16 + row16;
#pragma unroll
        for (int r = 0; r < 4; r++)
            dstb[(size_t)(r0 + r) * 128 + col] = f2bf(acc[n][r] * qs);
    }
}

// ---------------- fused wo-GEMM + residual + LN + ff-GEMM + residual ----------------
__global__ __launch_bounds__(256) void k_wolnff(const u16* __restrict__ X,
                                                const u16* __restrict__ Wo,
                                                const u16* __restrict__ Wff,
                                                const float* __restrict__ res,
                                                float* __restrict__ dst) {
    __shared__ alignas(16) u16 sX[64 * 128];
    __shared__ alignas(16) u16 sW1[128 * 128];
    __shared__ alignas(16) u16 sW2[128 * 128];
    int tid = threadIdx.x;
    int w = tid >> 6, l64 = tid & 63;
    int rbase = blockIdx.x * 64;
#pragma unroll
    for (int j = 0; j < 8; j++) {
        int e = j * 256 + tid;
        int r = e >> 4, cc = e & 15;
        int sw = ((cc ^ (r & 15)) << 3);
        *(u32x4*)&sW1[r * 128 + sw] = *(const u32x4*)&Wo[(r << 7) + (cc << 3)];
        *(u32x4*)&sW2[r * 128 + sw] = *(const u32x4*)&Wff[(r << 7) + (cc << 3)];
    }
#pragma unroll
    for (int j = 0; j < 4; j++) {
        int e = j * 256 + tid;
        int r = e >> 4, cc = e & 15;
        *(u32x4*)&sX[r * 128 + ((cc ^ (r & 15)) << 3)] =
            *(const u32x4*)&X[((rbase + r) << 7) + (cc << 3)];
    }
    __syncthreads();

    int row16 = l64 & 15, g = l64 >> 4;
    f32x4 zf = {0.f, 0.f, 0.f, 0.f};
    f32x4 acc[8];
#pragma unroll
    for (int n = 0; n < 8; n++) acc[n] = zf;
#pragma unroll
    for (int kk = 0; kk < 4; kk++) {
        int chunk = ((kk * 4 + g) ^ row16) << 3;
        bf16x8 a = ldb(&sX[(w * 16 + row16) * 128 + chunk]);
#pragma unroll
        for (int n = 0; n < 8; n++) {
            bf16x8 bfr = ldb(&sW1[(n * 16 + row16) * 128 + chunk]);
            acc[n] = mfma16(a, bfr, acc[n]);
        }
    }
    f32x4 vals[8];
#pragma unroll
    for (int n = 0; n < 8; n++) {
        int col = n * 16 + row16;
#pragma unroll
        for (int r = 0; r < 4; r++)
            vals[n][r] = acc[n][r] + res[(size_t)(rbase + w * 16 + g * 4 + r) * 128 + col];
    }
    float mean[4], rstd[4];
#pragma unroll
    for (int r = 0; r < 4; r++) {
        float s = 0.f, q = 0.f;
#pragma unroll
        for (int n = 0; n < 8; n++) {
            s += vals[n][r];
            q += vals[n][r] * vals[n][r];
        }
#pragma unroll
        for (int off = 1; off < 16; off <<= 1) {
            s += __shfl_xor(s, off);
            q += __shfl_xor(q, off);
        }
        mean[r] = s * (1.0f / 128.0f);
        float var = q * (1.0f / 128.0f) - mean[r] * mean[r];
        rstd[r] = rsqrtf(var + 1e-5f);
    }
    __syncthreads();
#pragma unroll
    for (int n = 0; n < 8; n++) {
        int col = n * 16 + row16;
        int cc = col >> 3;
#pragma unroll
        for (int r = 0; r < 4; r++) {
            int row = w * 16 + g * 4 + r;
            sX[row * 128 + ((cc ^ (row & 15)) << 3) + (row16 & 7)] =
                f2bf((vals[n][r] - mean[r]) * rstd[r]);
        }
    }
    __syncthreads();
    f32x4 acc2[8];
#pragma unroll
    for (int n = 0; n < 8; n++) acc2[n] = zf;
#pragma unroll
    for (int kk = 0; kk < 4; kk++) {
        int chunk = ((kk * 4 + g) ^ row16) << 3;
        bf16x8 a = ldb(&sX[(w * 16 + row16) * 128 + chunk]);
#pragma unroll
        for (int n = 0; n < 8; n++) {
            bf16x8 bfr = ldb(&sW2[(n * 16 + row16) * 128 + chunk]);
            acc2[n] = mfma16(a, bfr, acc2[n]);
        }
    }
#pragma unroll
    for (int n = 0; n < 8; n++) {
        int col = n * 16 + row16;
#pragma unroll
        for (int r = 0; r < 4; r++)
            dst[(size_t)(rbase + w * 16 + g * 4 + r) * 128 + col] = vals[n][r] + acc2[n][r];
    }
}

// ---------------- fused attention: K-doubled QK, pre-shuffled V, no-max exp2 softmax ----------------
// grid = 1024: blockIdx = bh*8 + qblk ; block = 512 (8 waves x 16 q-rows)
// QK (per 16-key tile): S^T = mfma16(A=K, B=Q), both frags carry d-slice (g&1)*8+i
//   (each d twice => S = 2*dot; 0.5 folded into Q prescale). Out: key=g*4+r, q=lane&15.
// PV (per 32-key pair): O^T = mfma16(A=Vshuf, B=P); V pre-shuffled so lane (d,g)'s 8 keys
//   {g*4+r, 16+g*4+r} are contiguous; chunk-XOR swizzle kills bank conflicts.
__global__ __launch_bounds__(512) void k_attn(const u16* __restrict__ Qg, const u16* __restrict__ Kg,
                                              const u16* __restrict__ Vg,
                                              const int* __restrict__ nsumI,
                                              u16* __restrict__ Og) {
    __shared__ alignas(16) u16 sVtP[16 * 1024];  // 32KB: [d][shuffled key pos], XOR-swizzled
    int tid = threadIdx.x;
    int w = tid >> 6, l = tid & 63;
    int bh = blockIdx.x >> 3;
    int qblk = blockIdx.x & 7;
    int b = bh >> 3, h = bh & 7;
    int row16 = l & 15, g = l >> 4;

    const u16* kg = Kg + (size_t)(b << 10) * 128 + (h << 4);
    const u16* vg = Vg + (size_t)(b << 10) * 128 + (h << 4);
#pragma unroll
    for (int j = 0; j < 4; j++) {
        int e = j * 512 + tid;
        int m = e >> 1, half = e & 1;
        u32x4 vv = *(const u32x4*)&vg[m * 128 + half * 8];
        union { u32x4 q; u16 s[8]; } u;
        u.q = vv;
        int within = m & 31;
        int pos = (m & ~31) + ((within >> 2) & 3) * 8 + (within >> 4) * 4 + (m & 3);
        int pc = pos >> 3, pw = pos & 7;
#pragma unroll
        for (int jj = 0; jj < 8; jj++) {
            int d = half * 8 + jj;
            sVtP[d * 1024 + ((pc ^ (d & 7)) << 3) + pw] = u.s[jj];
        }
    }
    __syncthreads();
    int nsum = nsumI[b];

    int qbase = qblk * 128 + w * 16;
    u16x8 z8 = {0, 0, 0, 0, 0, 0, 0, 0};
    const bf16x8 zb = __builtin_bit_cast(bf16x8, z8);
    f32x4 zf = {0.f, 0.f, 0.f, 0.f};
    int dofs = (g & 1) << 3;

    bool rowv = (qbase + row16) < nsum;
    bf16x8 qf = zb;
    if (rowv)  // pre-scaled Q (0.5*rsqrt(nsum)*log2e folded); invalid rows: S=0 -> P=1
        qf = ldb(&Qg[(size_t)((b << 10) + qbase + row16) * 128 + (h << 4) + dofs]);
    f32x4 oacc = zf;
    float lrun = 0.0f;

    const u16* vrow = &sVtP[row16 << 10];
    int vsw = row16 & 7;
    int p = 0;
    if (qbase < nsum) {  // wave has at least one valid q-row
        int full = nsum >> 5;
        for (; p < full; p++) {
            bf16x8 kf0 = ldb(&kg[(size_t)((p << 5) + row16) * 128 + dofs]);
            bf16x8 kf1 = ldb(&kg[(size_t)((p << 5) + 16 + row16) * 128 + dofs]);
            bf16x8 vf = ldb(&vrow[((((p << 2) + g) ^ vsw) << 3)]);
            f32x4 s0 = mfma16(kf0, qf, zf);
            f32x4 s1 = mfma16(kf1, qf, zf);
            float p0 = exp2f(s0[0]), p1 = exp2f(s0[1]), p2 = exp2f(s0[2]), p3 = exp2f(s0[3]);
            float p4 = exp2f(s1[0]), p5 = exp2f(s1[1]), p6 = exp2f(s1[2]), p7 = exp2f(s1[3]);
            lrun += ((p0 + p1) + (p2 + p3)) + ((p4 + p5) + (p6 + p7));
            bf16x8 pa = {(__bf16)p0, (__bf16)p1, (__bf16)p2, (__bf16)p3,
                         (__bf16)p4, (__bf16)p5, (__bf16)p6, (__bf16)p7};
            oacc = mfma16(vf, pa, oacc);
        }
        if (nsum & 31) {  // one partial pair
            bf16x8 kf0 = ldb(&kg[(size_t)((p << 5) + row16) * 128 + dofs]);
            bf16x8 kf1 = ldb(&kg[(size_t)((p << 5) + 16 + row16) * 128 + dofs]);
            bf16x8 vf = ldb(&vrow[((((p << 2) + g) ^ vsw) << 3)]);
            f32x4 s0 = mfma16(kf0, qf, zf);
            f32x4 s1 = mfma16(kf1, qf, zf);
            int kb_ = p << 5;
            float negfill = rowv ? -1.0e30f : 0.0f;  // invalid rows: P=1 on all cols
            float sv[8];
#pragma unroll
            for (int r = 0; r < 4; r++) {
                sv[r] = ((kb_ + (g << 2) + r) < nsum) ? s0[r] : negfill;
                sv[4 + r] = ((kb_ + 16 + (g << 2) + r) < nsum) ? s1[r] : negfill;
            }
            float p0 = exp2f(sv[0]), p1 = exp2f(sv[1]), p2 = exp2f(sv[2]), p3 = exp2f(sv[3]);
            float p4 = exp2f(sv[4]), p5 = exp2f(sv[5]), p6 = exp2f(sv[6]), p7 = exp2f(sv[7]);
            lrun += ((p0 + p1) + (p2 + p3)) + ((p4 + p5) + (p6 + p7));
            bf16x8 pa = {(__bf16)p0, (__bf16)p1, (__bf16)p2, (__bf16)p3,
                         (__bf16)p4, (__bf16)p5, (__bf16)p6, (__bf16)p7};
            oacc = mfma16(vf, pa, oacc);
            p++;
        }
    }
    if (qbase + 16 > nsum && p < 32) {  // waves holding invalid rows: constant P tail
        int ntail = 32 - p;
        __bf16 vcst = rowv ? (__bf16)0.0f : (__bf16)1.0f;
        bf16x8 pt = {vcst, vcst, vcst, vcst, vcst, vcst, vcst, vcst};
        if (!rowv) lrun += 8.0f * (float)ntail;
        for (; p < 32; p++) {
            bf16x8 vf = ldb(&vrow[((((p << 2) + g) ^ vsw) << 3)]);
            oacc = mfma16(vf, pt, oacc);
        }
    }

    float lr = lrun;
    lr += __shfl_xor(lr, 16);
    lr += __shfl_xor(lr, 32);
    float inv = 1.0f / lr;
    u16x4 ov;
#pragma unroll
    for (int r = 0; r < 4; r++) ov[r] = f2bf(oacc[r] * inv);
    int q = qbase + row16;
    *(u16x4*)&Og[(size_t)((b << 10) + q) * 128 + (h << 4) + (g << 2)] = ov;
}

extern "C" void kernel_launch(void* const* d_in, const int* in_sizes, int n_in,
                              void* d_out, int out_size, void* d_ws, size_t ws_size,
                              hipStream_t stream) {
    const float* emb     = (const float*)d_in[0];
    const int*   mask    = (const int*)d_in[1];
    const float* depth_w = (const float*)d_in[2];
    const float* depth_b = (const float*)d_in[3];
    const float* pt_w    = (const float*)d_in[4];
    const float* pt_b    = (const float*)d_in[5];
    const float* wq      = (const float*)d_in[6];
    const float* wk      = (const float*)d_in[7];
    const float* wv      = (const float*)d_in[8];
    const float* wo      = (const float*)d_in[9];
    const float* wff     = (const float*)d_in[10];
    float* out = (float*)d_out;
    char* ws = (char*)d_ws;

    float* f32a = (float*)(ws + 0);             // 8.4 MB conv ping-pong
    u16* qb    = (u16*)(ws + 8388608);
    u16* kb    = (u16*)(ws + 12582912);
    u16* vb    = (u16*)(ws + 16777216);
    u16* attnb = (u16*)(ws + 20971520);
    u16* wb    = (u16*)(ws + 25165824);
    u16* ptwb = wb;
    u16* wqb = wb + 65536;
    u16* wob = wb + 114688;
    u16* wffb = wb + 131072;
    int*   nsumI  = (int*)(ws + 25460736);
    float* scaleQ = (float*)(ws + 25460800);

    k_cvtw<<<576, 256, 0, stream>>>(pt_w, wq, wk, wv, wo, wff, wb);
    k_nsum<<<16, 256, 0, stream>>>(mask, nsumI, scaleQ);

    // conv layers ping-pong: emb -> f32a -> out -> f32a -> out
    const float* src[4] = {emb, f32a, out, f32a};
    float* dst[4] = {f32a, out, f32a, out};
    for (int i = 0; i < 4; i++) {
        k_convlayer<<<512, 256, 0, stream>>>(src[i], ptwb + i * 16384, depth_w + i * 896,
                                             depth_b + i * 128, pt_b + i * 128, dst[i]);
    }
    // LN + QKV (batched over y); Q pre-scaled by 0.5*rsqrt(nsum)*log2e
    {
        dim3 g3(256, 3);
        k_lngemm<<<g3, 256, 0, stream>>>(out, wqb, 16384, qb, 2097152, scaleQ);
    }
    k_attn<<<1024, 512, 0, stream>>>(qb, kb, vb, nsumI, attnb);
    // wo GEMM + residual + LN + ff GEMM + residual -> out
    k_wolnff<<<256, 256, 0, stream>>>(attnb, wob, wffb, out, out);
}

// Round 8
// 126.385 us; speedup vs baseline: 1.0587x; 1.0587x over previous
//
#include <hip/hip_runtime.h>

typedef unsigned short u16;
typedef float f32x4 __attribute__((ext_vector_type(4)));
typedef unsigned int u32x4 __attribute__((ext_vector_type(4)));
typedef unsigned short u16x4 __attribute__((ext_vector_type(4)));
typedef unsigned short u16x8 __attribute__((ext_vector_type(8)));
typedef __bf16 bf16x8 __attribute__((ext_vector_type(8)));

#define DEVFN static __device__ __forceinline__

DEVFN float bf2f(u16 u) {
    unsigned int i = ((unsigned int)u) << 16;
    float f;
    __builtin_memcpy(&f, &i, 4);
    return f;
}
DEVFN u16 f2bf(float f) {
    unsigned int i;
    __builtin_memcpy(&i, &f, 4);
    unsigned int r = i + 0x7fffu + ((i >> 16) & 1u);
    return (u16)(r >> 16);
}

DEVFN bf16x8 ldb(const u16* p) { return __builtin_bit_cast(bf16x8, *(const u16x8*)p); }

// 16x16x32: C/D: col=lane&15 (Brow), row=(lane>>4)*4+reg (Arow)  (HW-verified r2)
DEVFN f32x4 mfma16(bf16x8 a, bf16x8 b, f32x4 c) {
    return __builtin_amdgcn_mfma_f32_16x16x32_bf16(a, b, c, 0, 0, 0);
}

// ---------------- weight convert: fp32 -> bf16 ----------------
__global__ __launch_bounds__(256) void k_cvtw(const float* __restrict__ pt,
                                              const float* __restrict__ q,
                                              const float* __restrict__ k,
                                              const float* __restrict__ v,
                                              const float* __restrict__ o,
                                              const float* __restrict__ f,
                                              u16* __restrict__ dst) {
    int i = blockIdx.x * 256 + threadIdx.x;  // grid covers exactly 147456
    const float* s;
    int off;
    if (i < 65536)       { s = pt; off = i; }
    else if (i < 81920)  { s = q;  off = i - 65536; }
    else if (i < 98304)  { s = k;  off = i - 81920; }
    else if (i < 114688) { s = v;  off = i - 98304; }
    else if (i < 131072) { s = o;  off = i - 114688; }
    else                 { s = f;  off = i - 131072; }
    dst[i] = f2bf(s[off]);
}

// ---------------- per-batch mask sum + Q scale ----------------
__global__ __launch_bounds__(256) void k_nsum(const int* __restrict__ mask,
                                              int* __restrict__ nsumI,
                                              float* __restrict__ scaleQ) {
    __shared__ int sred[4];
    int tid = threadIdx.x, b = blockIdx.x;
    int4 mm = *(const int4*)&mask[(b << 10) + tid * 4];
    int part = mm.x + mm.y + mm.z + mm.w;
#pragma unroll
    for (int off = 1; off < 64; off <<= 1) part += __shfl_xor(part, off);
    if ((tid & 63) == 0) sred[tid >> 6] = part;
    __syncthreads();
    if (tid == 0) {
        int n = sred[0] + sred[1] + sred[2] + sred[3];
        nsumI[b] = n;
        // 0.5: QK uses K-doubled fragments (S = 2*dot); log2(e): exp2 softmax
        scaleQ[b] = 0.5f * rsqrtf((float)n) * 1.44269504089f;
    }
}

// ---------------- fused conv layer: LN + depthwise conv + pointwise GEMM + residual ----------------
__global__ __launch_bounds__(256) void k_convlayer(const float* __restrict__ x,
                                                   const u16* __restrict__ Wp,
                                                   const float* __restrict__ dw,
                                                   const float* __restrict__ db,
                                                   const float* __restrict__ pb,
                                                   float* __restrict__ dst) {
    __shared__ alignas(16) u16 lnv[38 * 128];    // LN'ed rows l0-3..l0+34
    __shared__ alignas(16) u16 convt[32 * 128];  // conv output, swizzled A-tile
    __shared__ alignas(16) u16 sW[128 * 128];    // pointwise W, swizzled
    __shared__ alignas(16) float sRes[32 * 128]; // fp32 residual rows
    int tid = threadIdx.x;
    int w = tid >> 6, l64 = tid & 63;
    int b = blockIdx.x >> 5, lt = blockIdx.x & 31;
    int l0 = lt << 5;
    const float* xb = x + ((size_t)(b << 10)) * 128;

#pragma unroll
    for (int j = 0; j < 8; j++) {
        int e = j * 256 + tid;
        int r = e >> 4, cc = e & 15;
        *(u32x4*)&sW[r * 128 + ((cc ^ (r & 15)) << 3)] = *(const u32x4*)&Wp[(r << 7) + (cc << 3)];
    }

    for (int r = w; r < 38; r += 4) {
        int gl = l0 - 3 + r;
        float2 v = {0.f, 0.f};
        bool ok = (gl >= 0) && (gl < 1024);
        if (ok) v = *(const float2*)&xb[(size_t)gl * 128 + (l64 << 1)];
        if (r >= 3 && r < 35) *(float2*)&sRes[(r - 3) * 128 + (l64 << 1)] = v;
        float s = v.x + v.y, q = v.x * v.x + v.y * v.y;
#pragma unroll
        for (int off = 1; off < 64; off <<= 1) {
            s += __shfl_xor(s, off);
            q += __shfl_xor(q, off);
        }
        float mean = s * (1.0f / 128.0f);
        float var = q * (1.0f / 128.0f) - mean * mean;
        float rs = rsqrtf(var + 1e-5f);
        unsigned int pk = 0;
        if (ok)
            pk = (unsigned int)f2bf((v.x - mean) * rs) | ((unsigned int)f2bf((v.y - mean) * rs) << 16);
        *(unsigned int*)&lnv[r * 128 + (l64 << 1)] = pk;
    }
    __syncthreads();

    // depthwise conv, sliding window: 14 LDS reads per thread, values kept in regs
    int cp = tid & 63;
    int ls = tid >> 6;
    float w0[7], w1[7];
#pragma unroll
    for (int k = 0; k < 7; k++) {
        w0[k] = dw[(cp * 2) * 7 + k];
        w1[k] = dw[(cp * 2 + 1) * 7 + k];
    }
    float b0 = db[cp * 2], b1 = db[cp * 2 + 1];
    float v0[14], v1[14];
#pragma unroll
    for (int k = 0; k < 14; k++) {
        unsigned int pk = *(const unsigned int*)&lnv[(ls * 8 + k) * 128 + (cp << 1)];
        v0[k] = bf2f((u16)(pk & 0xffffu));
        v1[k] = bf2f((u16)(pk >> 16));
    }
#pragma unroll
    for (int rr = 0; rr < 8; rr++) {
        int l = ls * 8 + rr;
        float a0 = b0, a1 = b1;
#pragma unroll
        for (int k = 0; k < 7; k++) {
            a0 += v0[rr + k] * w0[k];
            a1 += v1[rr + k] * w1[k];
        }
        int cc = cp >> 2;
        *(unsigned int*)&convt[l * 128 + ((cc ^ (l & 15)) << 3) + ((cp & 3) << 1)] =
            (unsigned int)f2bf(a0) | ((unsigned int)f2bf(a1) << 16);
    }
    __syncthreads();

    int row16 = l64 & 15, g = l64 >> 4;
    int mh = w >> 1, nh = w & 1;
    f32x4 zf = {0.f, 0.f, 0.f, 0.f};
    f32x4 acc[4] = {zf, zf, zf, zf};
#pragma unroll
    for (int kk = 0; kk < 4; kk++) {
        int chunk = ((kk * 4 + g) ^ row16) << 3;
        bf16x8 a = ldb(&convt[(mh * 16 + row16) * 128 + chunk]);
#pragma unroll
        for (int n = 0; n < 4; n++) {
            bf16x8 bfr = ldb(&sW[(nh * 64 + n * 16 + row16) * 128 + chunk]);
            acc[n] = mfma16(a, bfr, acc[n]);
        }
    }
#pragma unroll
    for (int n = 0; n < 4; n++) {
        int col = nh * 64 + n * 16 + row16;
        float bi = pb[col];
#pragma unroll
        for (int r = 0; r < 4; r++) {
            int lr = mh * 16 + g * 4 + r;
            float val = acc[n][r] + bi + sRes[lr * 128 + col];
            dst[((size_t)(b << 10) + l0 + lr) * 128 + col] = val;
        }
    }
}

// ---------------- fused LN + GEMM: Y = LN(X) @ W^T -> bf16 (QKV; Q pre-scaled) ----------------
__global__ __launch_bounds__(256) void k_lngemm(const float* __restrict__ x,
                                                const u16* __restrict__ Wb, int wstride,
                                                u16* __restrict__ dstb, int dstride,
                                                const float* __restrict__ scaleQ) {
    __shared__ alignas(16) u16 sX[64 * 128];
    __shared__ alignas(16) u16 sW[128 * 128];
    const u16* Wp = Wb + (size_t)blockIdx.y * wstride;
    dstb += (size_t)blockIdx.y * dstride;
    float qs = (blockIdx.y == 0) ? scaleQ[blockIdx.x >> 4] : 1.0f;
    int tid = threadIdx.x;
    int w = tid >> 6, l64 = tid & 63;
    int rbase = blockIdx.x * 64;

#pragma unroll
    for (int j = 0; j < 8; j++) {
        int e = j * 256 + tid;
        int r = e >> 4, cc = e & 15;
        *(u32x4*)&sW[r * 128 + ((cc ^ (r & 15)) << 3)] = *(const u32x4*)&Wp[(r << 7) + (cc << 3)];
    }
    for (int r = w; r < 64; r += 4) {
        float2 v = *(const float2*)&x[((size_t)(rbase + r)) * 128 + (l64 << 1)];
        float s = v.x + v.y, q = v.x * v.x + v.y * v.y;
#pragma unroll
        for (int off = 1; off < 64; off <<= 1) {
            s += __shfl_xor(s, off);
            q += __shfl_xor(q, off);
        }
        float mean = s * (1.0f / 128.0f);
        float var = q * (1.0f / 128.0f) - mean * mean;
        float rs = rsqrtf(var + 1e-5f);
        unsigned int pk = (unsigned int)f2bf((v.x - mean) * rs) |
                          ((unsigned int)f2bf((v.y - mean) * rs) << 16);
        int cc = l64 >> 2;
        *(unsigned int*)&sX[r * 128 + ((cc ^ (r & 15)) << 3) + ((l64 & 3) << 1)] = pk;
    }
    __syncthreads();

    int row16 = l64 & 15, g = l64 >> 4;
    f32x4 zf = {0.f, 0.f, 0.f, 0.f};
    f32x4 acc[8];
#pragma unroll
    for (int n = 0; n < 8; n++) acc[n] = zf;
#pragma unroll
    for (int kk = 0; kk < 4; kk++) {
        int chunk = ((kk * 4 + g) ^ row16) << 3;
        bf16x8 a = ldb(&sX[(w * 16 + row16) * 128 + chunk]);
#pragma unroll
        for (int n = 0; n < 8; n++) {
            bf16x8 bfr = ldb(&sW[(n * 16 + row16) * 128 + chunk]);
            acc[n] = mfma16(a, bfr, acc[n]);
        }
    }
    int r0 = rbase + w * 16 + g * 4;
#pragma unroll
    for (int n = 0; n < 8; n++) {
        int col = n * 16 + row16;
#pragma unroll
        for (int r = 0; r < 4; r++)
            dstb[(size_t)(r0 + r) * 128 + col] = f2bf(acc[n][r] * qs);
    }
}

// ---------------- fused wo-GEMM + residual + LN + ff-GEMM + residual ----------------
__global__ __launch_bounds__(256) void k_wolnff(const u16* __restrict__ X,
                                                const u16* __restrict__ Wo,
                                                const u16* __restrict__ Wff,
                                                const float* __restrict__ res,
                                                float* __restrict__ dst) {
    __shared__ alignas(16) u16 sX[64 * 128];
    __shared__ alignas(16) u16 sW1[128 * 128];
    __shared__ alignas(16) u16 sW2[128 * 128];
    int tid = threadIdx.x;
    int w = tid >> 6, l64 = tid & 63;
    int rbase = blockIdx.x * 64;
#pragma unroll
    for (int j = 0; j < 8; j++) {
        int e = j * 256 + tid;
        int r = e >> 4, cc = e & 15;
        int sw = ((cc ^ (r & 15)) << 3);
        *(u32x4*)&sW1[r * 128 + sw] = *(const u32x4*)&Wo[(r << 7) + (cc << 3)];
        *(u32x4*)&sW2[r * 128 + sw] = *(const u32x4*)&Wff[(r << 7) + (cc << 3)];
    }
#pragma unroll
    for (int j = 0; j < 4; j++) {
        int e = j * 256 + tid;
        int r = e >> 4, cc = e & 15;
        *(u32x4*)&sX[r * 128 + ((cc ^ (r & 15)) << 3)] =
            *(const u32x4*)&X[((rbase + r) << 7) + (cc << 3)];
    }
    __syncthreads();

    int row16 = l64 & 15, g = l64 >> 4;
    f32x4 zf = {0.f, 0.f, 0.f, 0.f};
    f32x4 acc[8];
#pragma unroll
    for (int n = 0; n < 8; n++) acc[n] = zf;
#pragma unroll
    for (int kk = 0; kk < 4; kk++) {
        int chunk = ((kk * 4 + g) ^ row16) << 3;
        bf16x8 a = ldb(&sX[(w * 16 + row16) * 128 + chunk]);
#pragma unroll
        for (int n = 0; n < 8; n++) {
            bf16x8 bfr = ldb(&sW1[(n * 16 + row16) * 128 + chunk]);
            acc[n] = mfma16(a, bfr, acc[n]);
        }
    }
    f32x4 vals[8];
#pragma unroll
    for (int n = 0; n < 8; n++) {
        int col = n * 16 + row16;
#pragma unroll
        for (int r = 0; r < 4; r++)
            vals[n][r] = acc[n][r] + res[(size_t)(rbase + w * 16 + g * 4 + r) * 128 + col];
    }
    float mean[4], rstd[4];
#pragma unroll
    for (int r = 0; r < 4; r++) {
        float s = 0.f, q = 0.f;
#pragma unroll
        for (int n = 0; n < 8; n++) {
            s += vals[n][r];
            q += vals[n][r] * vals[n][r];
        }
#pragma unroll
        for (int off = 1; off < 16; off <<= 1) {
            s += __shfl_xor(s, off);
            q += __shfl_xor(q, off);
        }
        mean[r] = s * (1.0f / 128.0f);
        float var = q * (1.0f / 128.0f) - mean[r] * mean[r];
        rstd[r] = rsqrtf(var + 1e-5f);
    }
    __syncthreads();
#pragma unroll
    for (int n = 0; n < 8; n++) {
        int col = n * 16 + row16;
        int cc = col >> 3;
#pragma unroll
        for (int r = 0; r < 4; r++) {
            int row = w * 16 + g * 4 + r;
            sX[row * 128 + ((cc ^ (row & 15)) << 3) + (row16 & 7)] =
                f2bf((vals[n][r] - mean[r]) * rstd[r]);
        }
    }
    __syncthreads();
    f32x4 acc2[8];
#pragma unroll
    for (int n = 0; n < 8; n++) acc2[n] = zf;
#pragma unroll
    for (int kk = 0; kk < 4; kk++) {
        int chunk = ((kk * 4 + g) ^ row16) << 3;
        bf16x8 a = ldb(&sX[(w * 16 + row16) * 128 + chunk]);
#pragma unroll
        for (int n = 0; n < 8; n++) {
            bf16x8 bfr = ldb(&sW2[(n * 16 + row16) * 128 + chunk]);
            acc2[n] = mfma16(a, bfr, acc2[n]);
        }
    }
#pragma unroll
    for (int n = 0; n < 8; n++) {
        int col = n * 16 + row16;
#pragma unroll
        for (int r = 0; r < 4; r++)
            dst[(size_t)(rbase + w * 16 + g * 4 + r) * 128 + col] = vals[n][r] + acc2[n][r];
    }
}

// ---------------- fused attention v3: QT=2 tiles/wave, XCD-affine blocks, linear-addr V ----------------
// grid = 1024: bh = blockIdx & 127 (b*8+h), oct = blockIdx >> 7  (same-bh blocks share XCD)
// block = 256 thr (4 waves); wave covers 32 q-rows = 2 tiles of 16.
// QK: S^T = mfma16(A=K, B=Q), K-doubled d-slice (g&1)*8+i; S=2*dot, 0.5 in Q prescale.
//     Out: key = g*4+r (s0) / +16 (s1), q = lane&15.
// PV: O^T = mfma16(A=Vshuf, B=P); V LDS [16][VSTR], key-shuffled pos, bank shift 4/row.
#define VSTR 1032
__global__ __launch_bounds__(256) void k_attn(const u16* __restrict__ Qg, const u16* __restrict__ Kg,
                                              const u16* __restrict__ Vg,
                                              const int* __restrict__ nsumI,
                                              u16* __restrict__ Og) {
    __shared__ alignas(16) u16 sVt[16 * VSTR + 8];
    int tid = threadIdx.x;
    int w = tid >> 6, l = tid & 63;
    int bh = blockIdx.x & 127;
    int oct = blockIdx.x >> 7;
    int b = bh >> 3, h = bh & 7;
    int row16 = l & 15, g = l >> 4;

    const u16* kg = Kg + (size_t)(b << 10) * 128 + (h << 4);
    const u16* vg = Vg + (size_t)(b << 10) * 128 + (h << 4);
#pragma unroll
    for (int j = 0; j < 8; j++) {
        int e = j * 256 + tid;
        int m = e >> 1, half = e & 1;
        u32x4 vv = *(const u32x4*)&vg[m * 128 + half * 8];
        union { u32x4 q; u16 s[8]; } u;
        u.q = vv;
        int within = m & 31;
        int pos = (m & ~31) + ((within >> 2) & 3) * 8 + (within >> 4) * 4 + (m & 3);
#pragma unroll
        for (int jj = 0; jj < 8; jj++) {
            int d = half * 8 + jj;
            sVt[d * VSTR + pos] = u.s[jj];
        }
    }
    __syncthreads();
    int nsum = nsumI[b];

    int qbase0 = oct * 128 + w * 32;  // tile t covers rows qbase0 + t*16 + row16
    u16x8 z8 = {0, 0, 0, 0, 0, 0, 0, 0};
    const bf16x8 zb = __builtin_bit_cast(bf16x8, z8);
    f32x4 zf = {0.f, 0.f, 0.f, 0.f};
    int dofs = (g & 1) << 3;

    bool rowv[2];
    bf16x8 qf[2];
    f32x4 oacc[2] = {zf, zf};
    float lrun[2] = {0.0f, 0.0f};
#pragma unroll
    for (int t = 0; t < 2; t++) {
        int q = qbase0 + t * 16 + row16;
        rowv[t] = q < nsum;
        qf[t] = zb;
        if (rowv[t])  // pre-scaled Q; invalid rows: S=0 -> P=1
            qf[t] = ldb(&Qg[(size_t)((b << 10) + q) * 128 + (h << 4) + dofs]);
    }

    const u16* kl = kg + row16 * 128 + dofs;           // per-lane K ptr, +8192B/pair
    const u16* vl = &sVt[row16 * VSTR + (g << 3)];     // per-lane V ptr, +64B/pair
    int p = 0;
    if (qbase0 < nsum) {
        int full = nsum >> 5;
#pragma unroll 2
        for (; p < full; p++) {
            bf16x8 kf0 = ldb(kl);
            bf16x8 kf1 = ldb(kl + 16 * 128);
            bf16x8 vf = ldb(&vl[p << 5]);
            kl += 32 * 128;
#pragma unroll
            for (int t = 0; t < 2; t++) {
                f32x4 s0 = mfma16(kf0, qf[t], zf);
                f32x4 s1 = mfma16(kf1, qf[t], zf);
                float p0 = exp2f(s0[0]), p1 = exp2f(s0[1]), p2 = exp2f(s0[2]), p3 = exp2f(s0[3]);
                float p4 = exp2f(s1[0]), p5 = exp2f(s1[1]), p6 = exp2f(s1[2]), p7 = exp2f(s1[3]);
                lrun[t] += ((p0 + p1) + (p2 + p3)) + ((p4 + p5) + (p6 + p7));
                bf16x8 pa = {(__bf16)p0, (__bf16)p1, (__bf16)p2, (__bf16)p3,
                             (__bf16)p4, (__bf16)p5, (__bf16)p6, (__bf16)p7};
                oacc[t] = mfma16(vf, pa, oacc[t]);
            }
        }
        if (nsum & 31) {  // one partial pair
            bf16x8 kf0 = ldb(kl);
            bf16x8 kf1 = ldb(kl + 16 * 128);
            bf16x8 vf = ldb(&vl[p << 5]);
            int kb_ = p << 5;
#pragma unroll
            for (int t = 0; t < 2; t++) {
                f32x4 s0 = mfma16(kf0, qf[t], zf);
                f32x4 s1 = mfma16(kf1, qf[t], zf);
                float negfill = rowv[t] ? -1.0e30f : 0.0f;  // invalid rows: P=1 on all cols
                float sv[8];
#pragma unroll
                for (int r = 0; r < 4; r++) {
                    sv[r] = ((kb_ + (g << 2) + r) < nsum) ? s0[r] : negfill;
                    sv[4 + r] = ((kb_ + 16 + (g << 2) + r) < nsum) ? s1[r] : negfill;
                }
                float p0 = exp2f(sv[0]), p1 = exp2f(sv[1]), p2 = exp2f(sv[2]), p3 = exp2f(sv[3]);
                float p4 = exp2f(sv[4]), p5 = exp2f(sv[5]), p6 = exp2f(sv[6]), p7 = exp2f(sv[7]);
                lrun[t] += ((p0 + p1) + (p2 + p3)) + ((p4 + p5) + (p6 + p7));
                bf16x8 pa = {(__bf16)p0, (__bf16)p1, (__bf16)p2, (__bf16)p3,
                             (__bf16)p4, (__bf16)p5, (__bf16)p6, (__bf16)p7};
                oacc[t] = mfma16(vf, pa, oacc[t]);
            }
            p++;
        }
    }
    // tail: pairs with no valid keys; only tiles containing invalid rows participate (P=1 there)
    bool act0 = (qbase0 + 16 > nsum);
    bool act1 = (qbase0 + 32 > nsum);
    if (act1 && p < 32) {
        int ntail = 32 - p;
        __bf16 c0 = rowv[0] ? (__bf16)0.0f : (__bf16)1.0f;
        __bf16 c1 = rowv[1] ? (__bf16)0.0f : (__bf16)1.0f;
        bf16x8 pt0 = {c0, c0, c0, c0, c0, c0, c0, c0};
        bf16x8 pt1 = {c1, c1, c1, c1, c1, c1, c1, c1};
        if (act0 && !rowv[0]) lrun[0] += 8.0f * (float)ntail;
        if (!rowv[1]) lrun[1] += 8.0f * (float)ntail;
        for (; p < 32; p++) {
            bf16x8 vf = ldb(&vl[p << 5]);
            if (act0) oacc[0] = mfma16(vf, pt0, oacc[0]);
            oacc[1] = mfma16(vf, pt1, oacc[1]);
        }
    }

#pragma unroll
    for (int t = 0; t < 2; t++) {
        float lr = lrun[t];
        lr += __shfl_xor(lr, 16);
        lr += __shfl_xor(lr, 32);
        float inv = 1.0f / lr;
        u16x4 ov;
#pragma unroll
        for (int r = 0; r < 4; r++) ov[r] = f2bf(oacc[t][r] * inv);
        int q = qbase0 + t * 16 + row16;
        *(u16x4*)&Og[(size_t)((b << 10) + q) * 128 + (h << 4) + (g << 2)] = ov;
    }
}

extern "C" void kernel_launch(void* const* d_in, const int* in_sizes, int n_in,
                              void* d_out, int out_size, void* d_ws, size_t ws_size,
                              hipStream_t stream) {
    const float* emb     = (const float*)d_in[0];
    const int*   mask    = (const int*)d_in[1];
    const float* depth_w = (const float*)d_in[2];
    const float* depth_b = (const float*)d_in[3];
    const float* pt_w    = (const float*)d_in[4];
    const float* pt_b    = (const float*)d_in[5];
    const float* wq      = (const float*)d_in[6];
    const float* wk      = (const float*)d_in[7];
    const float* wv      = (const float*)d_in[8];
    const float* wo      = (const float*)d_in[9];
    const float* wff     = (const float*)d_in[10];
    float* out = (float*)d_out;
    char* ws = (char*)d_ws;

    float* f32a = (float*)(ws + 0);             // 8.4 MB conv ping-pong
    u16* qb    = (u16*)(ws + 8388608);
    u16* kb    = (u16*)(ws + 12582912);
    u16* vb    = (u16*)(ws + 16777216);
    u16* attnb = (u16*)(ws + 20971520);
    u16* wb    = (u16*)(ws + 25165824);
    u16* ptwb = wb;
    u16* wqb = wb + 65536;
    u16* wob = wb + 114688;
    u16* wffb = wb + 131072;
    int*   nsumI  = (int*)(ws + 25460736);
    float* scaleQ = (float*)(ws + 25460800);

    k_cvtw<<<576, 256, 0, stream>>>(pt_w, wq, wk, wv, wo, wff, wb);
    k_nsum<<<16, 256, 0, stream>>>(mask, nsumI, scaleQ);

    // conv layers ping-pong: emb -> f32a -> out -> f32a -> out
    const float* src[4] = {emb, f32a, out, f32a};
    float* dst[4] = {f32a, out, f32a, out};
    for (int i = 0; i < 4; i++) {
        k_convlayer<<<512, 256, 0, stream>>>(src[i], ptwb + i * 16384, depth_w + i * 896,
                                             depth_b + i * 128, pt_b + i * 128, dst[i]);
    }
    // LN + QKV (batched over y); Q pre-scaled by 0.5*rsqrt(nsum)*log2e
    {
        dim3 g3(256, 3);
        k_lngemm<<<g3, 256, 0, stream>>>(out, wqb, 16384, qb, 2097152, scaleQ);
    }
    k_attn<<<1024, 256, 0, stream>>>(qb, kb, vb, nsumI, attnb);
    // wo GEMM + residual + LN + ff GEMM + residual -> out
    k_wolnff<<<256, 256, 0, stream>>>(attnb, wob, wffb, out, out);
}